// Round 1
// baseline (155579.248 us; speedup 1.0000x reference)
//
#include <hip/hip_runtime.h>
#include <math.h>

// Problem constants
#define LEAKC 0.3f
static constexpr int Bsz = 64;    // batch
static constexpr int Tt  = 512;   // time steps
static constexpr int INF = 256;   // layer0 input features
static constexpr int Hf  = 512;   // hidden
static constexpr int Rf  = 512;   // reservoir
static constexpr int OUTF = 10;

__device__ __forceinline__ float sigmoidf_(float x) {
    return 1.0f / (1.0f + __expf(-x));
}

// Accumulate acc[0..3] += sum_k act[k][b] * W[k][j0..j0+3]
// act: feature-major [K][64], W row-major with row stride 512.
__device__ __forceinline__ void gemv_seg(const float* __restrict__ act,
                                         const float* __restrict__ W,
                                         int K, int b, int j0, float acc[4]) {
    const float* ap = act + b;
    const float* wp = W + j0;
#pragma unroll 4
    for (int k = 0; k < K; ++k) {
        float xv = ap[k * 64];                                   // coalesced (lane=b)
        const float4 w = *reinterpret_cast<const float4*>(wp + k * 512); // wave-broadcast
        acc[0] = fmaf(w.x, xv, acc[0]);
        acc[1] = fmaf(w.y, xv, acc[1]);
        acc[2] = fmaf(w.z, xv, acc[2]);
        acc[3] = fmaf(w.w, xv, acc[3]);
    }
}

// x (B,T,IN) -> xT (T,IN,B)
__global__ __launch_bounds__(256) void transpose_x_k(const float* __restrict__ x,
                                                     float* __restrict__ xT) {
    __shared__ float tile[64][65];
    int t  = blockIdx.x;
    int k0 = blockIdx.y * 64;
    int tid = threadIdx.x;
#pragma unroll
    for (int i = 0; i < 16; ++i) {
        int idx = i * 256 + tid;
        int bb = idx >> 6, kk = idx & 63;
        tile[bb][kk] = x[(size_t)bb * Tt * INF + (size_t)t * INF + k0 + kk];
    }
    __syncthreads();
#pragma unroll
    for (int i = 0; i < 16; ++i) {
        int idx = i * 256 + tid;
        int kk = idx >> 6, bb = idx & 63;
        xT[(size_t)t * INF * 64 + (size_t)(k0 + kk) * 64 + bb] = tile[bb][kk];
    }
}

// Phase 1: gates that depend only on previous-step state.
// gate 0: r_new = 0.7*r + 0.3*tanh(x@Win + r@Wres)
// gate 1: z     = sigmoid(x@Wz_x + h@Wz_h + bz)
// gate 2: rh    = sigmoid(x@Wr_x + h@Wr_h + br) * h
// gate 3: gx    = x@Wg_x            (partial pre-activation for g)
__global__ __launch_bounds__(256) void phase1_k(
    const float* __restrict__ xT, int lin, int t,
    const float* __restrict__ rcur, float* __restrict__ rnew,
    const float* __restrict__ hcur,
    float* __restrict__ zT, float* __restrict__ rhT, float* __restrict__ gxT,
    const float* __restrict__ Win, const float* __restrict__ Wres,
    const float* __restrict__ Wz, const float* __restrict__ bz,
    const float* __restrict__ Wr, const float* __restrict__ br,
    const float* __restrict__ Wg) {
    int tid = threadIdx.x;
    int b = tid & 63, jg = tid >> 6;
    int j0 = blockIdx.x * 16 + jg * 4;
    const float* xt = xT + (size_t)t * lin * 64;
    float acc[4] = {0.f, 0.f, 0.f, 0.f};
    int gate = blockIdx.y;
    if (gate == 0) {
        gemv_seg(xt, Win, lin, b, j0, acc);
        gemv_seg(rcur, Wres, Rf, b, j0, acc);
#pragma unroll
        for (int jj = 0; jj < 4; ++jj) {
            int j = j0 + jj;
            float ro = rcur[j * 64 + b];
            rnew[j * 64 + b] = (1.0f - LEAKC) * ro + LEAKC * tanhf(acc[jj]);
        }
    } else if (gate == 1) {
        gemv_seg(xt, Wz, lin, b, j0, acc);
        gemv_seg(hcur, Wz + (size_t)lin * Hf, Hf, b, j0, acc);
#pragma unroll
        for (int jj = 0; jj < 4; ++jj) {
            int j = j0 + jj;
            zT[j * 64 + b] = sigmoidf_(acc[jj] + bz[j]);
        }
    } else if (gate == 2) {
        gemv_seg(xt, Wr, lin, b, j0, acc);
        gemv_seg(hcur, Wr + (size_t)lin * Hf, Hf, b, j0, acc);
#pragma unroll
        for (int jj = 0; jj < 4; ++jj) {
            int j = j0 + jj;
            rhT[j * 64 + b] = sigmoidf_(acc[jj] + br[j]) * hcur[j * 64 + b];
        }
    } else {
        gemv_seg(xt, Wg, lin, b, j0, acc);
#pragma unroll
        for (int jj = 0; jj < 4; ++jj) {
            int j = j0 + jj;
            gxT[j * 64 + b] = acc[jj];
        }
    }
}

// Phase 2:
// gate 0: cand = tanh(x@Wc_x + rh@Wc_h + bc); h_gru = (1-z)h + z*cand
// gate 1: p    = tanh(r_new@Wp + bp)
// gate 2: gg   = gx + r_new@Wg_r     (partial pre-activation for g)
__global__ __launch_bounds__(256) void phase2_k(
    const float* __restrict__ xT, int lin, int t,
    const float* __restrict__ rnew, const float* __restrict__ hcur,
    const float* __restrict__ zT, const float* __restrict__ rhT,
    const float* __restrict__ gxT,
    float* __restrict__ hgT, float* __restrict__ pT, float* __restrict__ ggT,
    const float* __restrict__ Wc, const float* __restrict__ bc,
    const float* __restrict__ Wp, const float* __restrict__ bp,
    const float* __restrict__ Wg) {
    int tid = threadIdx.x;
    int b = tid & 63, jg = tid >> 6;
    int j0 = blockIdx.x * 16 + jg * 4;
    const float* xt = xT + (size_t)t * lin * 64;
    float acc[4] = {0.f, 0.f, 0.f, 0.f};
    int gate = blockIdx.y;
    if (gate == 0) {
        gemv_seg(xt, Wc, lin, b, j0, acc);
        gemv_seg(rhT, Wc + (size_t)lin * Hf, Hf, b, j0, acc);
#pragma unroll
        for (int jj = 0; jj < 4; ++jj) {
            int j = j0 + jj;
            float cand = tanhf(acc[jj] + bc[j]);
            float z = zT[j * 64 + b];
            float h = hcur[j * 64 + b];
            hgT[j * 64 + b] = (1.0f - z) * h + z * cand;
        }
    } else if (gate == 1) {
        gemv_seg(rnew, Wp, Rf, b, j0, acc);
#pragma unroll
        for (int jj = 0; jj < 4; ++jj) {
            int j = j0 + jj;
            pT[j * 64 + b] = tanhf(acc[jj] + bp[j]);
        }
    } else {
        gemv_seg(rnew, Wg + (size_t)(lin + Hf) * Hf, Rf, b, j0, acc);
#pragma unroll
        for (int jj = 0; jj < 4; ++jj) {
            int j = j0 + jj;
            ggT[j * 64 + b] = gxT[j * 64 + b] + acc[jj];
        }
    }
}

// Phase 3: g = sigmoid(gg + h_gru@Wg_h + bg); h_new = (1-g)h_gru + g*p
__global__ __launch_bounds__(256) void phase3_k(
    int lin, int t,
    const float* __restrict__ hgT, const float* __restrict__ pT,
    const float* __restrict__ ggT,
    float* __restrict__ hnext, float* __restrict__ y,
    const float* __restrict__ Wg, const float* __restrict__ bg) {
    int tid = threadIdx.x;
    int b = tid & 63, jg = tid >> 6;
    int j0 = blockIdx.x * 16 + jg * 4;
    float acc[4] = {0.f, 0.f, 0.f, 0.f};
    gemv_seg(hgT, Wg + (size_t)lin * Hf, Hf, b, j0, acc);
#pragma unroll
    for (int jj = 0; jj < 4; ++jj) {
        int j = j0 + jj;
        float g = sigmoidf_(acc[jj] + ggT[j * 64 + b] + bg[j]);
        float hg = hgT[j * 64 + b];
        float hn = (1.0f - g) * hg + g * pT[j * 64 + b];
        hnext[j * 64 + b] = hn;
        if (y) y[(size_t)t * Hf * 64 + j * 64 + b] = hn;
    }
}

// Head: hid = relu(last@Wo1 + bo1)
__global__ __launch_bounds__(256) void head1_k(const float* __restrict__ hlast,
                                               const float* __restrict__ Wo1,
                                               const float* __restrict__ bo1,
                                               float* __restrict__ hidT) {
    int tid = threadIdx.x;
    int b = tid & 63, jg = tid >> 6;
    int j0 = blockIdx.x * 16 + jg * 4;
    float acc[4] = {0.f, 0.f, 0.f, 0.f};
    gemv_seg(hlast, Wo1, Hf, b, j0, acc);
#pragma unroll
    for (int jj = 0; jj < 4; ++jj) {
        int j = j0 + jj;
        hidT[j * 64 + b] = fmaxf(acc[jj] + bo1[j], 0.f);
    }
}

// out[b][o] = hid[b]@Wo2[:,o] + bo2[o]
__global__ __launch_bounds__(640) void head2_k(const float* __restrict__ hidT,
                                               const float* __restrict__ Wo2,
                                               const float* __restrict__ bo2,
                                               float* __restrict__ out) {
    int tid = threadIdx.x;
    if (tid >= Bsz * OUTF) return;
    int b = tid / OUTF, o = tid % OUTF;
    float acc = 0.f;
    for (int k = 0; k < Hf; ++k)
        acc = fmaf(hidT[k * 64 + b], Wo2[k * OUTF + o], acc);
    out[tid] = acc + bo2[o];
}

struct LayerW {
    const float *Win, *Wres, *Wz, *bz, *Wr, *br, *Wc, *bc, *Wg, *bg, *Wp, *bp;
    int lin;
};

extern "C" void kernel_launch(void* const* d_in, const int* in_sizes, int n_in,
                              void* d_out, int out_size, void* d_ws, size_t ws_size,
                              hipStream_t stream) {
    const float* x = (const float*)d_in[0];
    LayerW L[2];
    int idx = 1;
    for (int li = 0; li < 2; ++li) {
        L[li].Win  = (const float*)d_in[idx++];
        L[li].Wres = (const float*)d_in[idx++];
        L[li].Wz   = (const float*)d_in[idx++];
        L[li].bz   = (const float*)d_in[idx++];
        L[li].Wr   = (const float*)d_in[idx++];
        L[li].br   = (const float*)d_in[idx++];
        L[li].Wc   = (const float*)d_in[idx++];
        L[li].bc   = (const float*)d_in[idx++];
        L[li].Wg   = (const float*)d_in[idx++];
        L[li].bg   = (const float*)d_in[idx++];
        L[li].Wp   = (const float*)d_in[idx++];
        L[li].bp   = (const float*)d_in[idx++];
        L[li].lin  = (li == 0) ? INF : Hf;
    }
    const float* Wo1 = (const float*)d_in[idx++];
    const float* bo1 = (const float*)d_in[idx++];
    const float* Wo2 = (const float*)d_in[idx++];
    const float* bo2 = (const float*)d_in[idx++];

    // workspace carve-up
    char* ws = (char*)d_ws;
    size_t off = 0;
    auto walloc = [&](size_t bytes) -> float* {
        float* p = (float*)(ws + off);
        off += (bytes + 255) & ~(size_t)255;
        return p;
    };
    const size_t STATE = (size_t)Hf * 64 * sizeof(float); // 128 KiB
    float* xT0 = walloc((size_t)Tt * INF * 64 * sizeof(float)); // 33.5 MB
    float* y0  = walloc((size_t)Tt * Hf * 64 * sizeof(float));  // 67 MB
    float* rA  = walloc(STATE);
    float* rB  = walloc(STATE);
    float* hA  = walloc(STATE);
    float* hB  = walloc(STATE);
    float* zT  = walloc(STATE);
    float* rhT = walloc(STATE);
    float* gxT = walloc(STATE);
    float* hgT = walloc(STATE);
    float* pT  = walloc(STATE);
    float* ggT = walloc(STATE);
    float* hidT = walloc(STATE);
    (void)ws_size;

    transpose_x_k<<<dim3(Tt, INF / 64), 256, 0, stream>>>(x, xT0);

    for (int li = 0; li < 2; ++li) {
        const LayerW& P = L[li];
        const float* xT = (li == 0) ? xT0 : y0;
        hipMemsetAsync(rA, 0, STATE, stream);
        hipMemsetAsync(hA, 0, STATE, stream);
        float *rc = rA, *rn = rB, *hc = hA, *hnx = hB;
        for (int t = 0; t < Tt; ++t) {
            phase1_k<<<dim3(32, 4), 256, 0, stream>>>(
                xT, P.lin, t, rc, rn, hc, zT, rhT, gxT,
                P.Win, P.Wres, P.Wz, P.bz, P.Wr, P.br, P.Wg);
            phase2_k<<<dim3(32, 3), 256, 0, stream>>>(
                xT, P.lin, t, rn, hc, zT, rhT, gxT, hgT, pT, ggT,
                P.Wc, P.bc, P.Wp, P.bp, P.Wg);
            phase3_k<<<dim3(32, 1), 256, 0, stream>>>(
                P.lin, t, hgT, pT, ggT, hnx, (li == 0) ? y0 : nullptr,
                P.Wg, P.bg);
            float* tmp = rc; rc = rn; rn = tmp;
            tmp = hc; hc = hnx; hnx = tmp;
        }
        if (li == 1) {
            head1_k<<<dim3(32, 1), 256, 0, stream>>>(hc, Wo1, bo1, hidT);
            head2_k<<<dim3(1, 1), 640, 0, stream>>>(hidT, Wo2, bo2, (float*)d_out);
        }
    }
}

// Round 2
// 83533.716 us; speedup vs baseline: 1.8625x; 1.8625x over previous
//
#include <hip/hip_runtime.h>
#include <math.h>

static constexpr int Bsz = 64;
static constexpr int Tt  = 512;
static constexpr int INF = 256;
static constexpr int Hf  = 512;
static constexpr int Rf  = 512;
static constexpr int OUTF = 10;
static constexpr int NBLK = 256;
static constexpr int NTHR = 512;
static constexpr unsigned SMEM_BYTES = 65536; // layer1: 49152 weights + 16384 partials

__device__ __forceinline__ float sigmoidf_(float x) {
    return 1.0f / (1.0f + __expf(-x));
}

// Flag-array grid barrier: block i publishes flags[i]=gen (release, agent scope);
// threads 0..NBLK-1 each poll one flag. No single-counter atomic contention.
__device__ __forceinline__ void gsync(unsigned* __restrict__ flags, unsigned gen) {
    __syncthreads();                       // all block work done, vmcnt drained per wave
    if (threadIdx.x == 0) {
        __threadfence();                   // release: flush this CU/XCD caches
        __hip_atomic_store(&flags[blockIdx.x], gen, __ATOMIC_RELEASE, __HIP_MEMORY_SCOPE_AGENT);
    }
    if (threadIdx.x < NBLK) {
        while (__hip_atomic_load(&flags[threadIdx.x], __ATOMIC_RELAXED, __HIP_MEMORY_SCOPE_AGENT) < gen) {
            __builtin_amdgcn_s_sleep(1);
        }
    }
    __syncthreads();
    if (threadIdx.x == 0) __threadfence(); // acquire: invalidate stale lines
    __syncthreads();
}

// x (B,T,IN) -> xT (T,IN,B)
__global__ __launch_bounds__(256) void transpose_x_k(const float* __restrict__ x,
                                                     float* __restrict__ xT) {
    __shared__ float tile[64][65];
    int t  = blockIdx.x;
    int k0 = blockIdx.y * 64;
    int tid = threadIdx.x;
#pragma unroll
    for (int i = 0; i < 16; ++i) {
        int idx = i * 256 + tid;
        int bb = idx >> 6, kk = idx & 63;
        tile[bb][kk] = x[(size_t)bb * Tt * INF + (size_t)t * INF + k0 + kk];
    }
    __syncthreads();
#pragma unroll
    for (int i = 0; i < 16; ++i) {
        int idx = i * 256 + tid;
        int kk = idx >> 6, bb = idx & 63;
        xT[(size_t)t * INF * 64 + (size_t)(k0 + kk) * 64 + bb] = tile[bb][kk];
    }
}

// Persistent per-layer kernel. 256 blocks x 512 threads; block bk owns cols
// {2bk, 2bk+1} of every weight matrix, LDS-resident. 3 phases + 3 grid syncs
// per time step. States are feature-major [512][64] in global ws.
template<int LIN, bool WRITE_Y>
__global__ __launch_bounds__(NTHR) void esn_persist_k(
    const float* __restrict__ xT, float* __restrict__ y,
    float* __restrict__ rA, float* __restrict__ rB,
    float* __restrict__ hA, float* __restrict__ hB,
    float* __restrict__ zT, float* __restrict__ rhT, float* __restrict__ gxT,
    float* __restrict__ hgT, float* __restrict__ pT, float* __restrict__ ggT,
    const float* __restrict__ Win, const float* __restrict__ Wres,
    const float* __restrict__ Wz, const float* __restrict__ bz,
    const float* __restrict__ Wr, const float* __restrict__ br,
    const float* __restrict__ Wc, const float* __restrict__ bc,
    const float* __restrict__ Wg, const float* __restrict__ bg,
    const float* __restrict__ Wp, const float* __restrict__ bp,
    unsigned* __restrict__ flags)
{
    extern __shared__ float2 sm2[];
    float2* sRES = sm2;                    // [LIN+512): rows of [Win;Wres]
    float2* sZ   = sRES + (LIN + Hf);      // Wz rows
    float2* sR   = sZ + (LIN + Hf);        // Wr rows
    float2* sC   = sR + (LIN + Hf);        // Wc rows
    float2* sGx  = sC + (LIN + Hf);        // Wg rows [0,LIN)
    float2* sGh  = sGx + LIN;              // Wg rows [LIN, LIN+512)
    float2* sGr  = sGh + Hf;               // Wg rows [LIN+512, LIN+1024)
    float2* sP   = sGr + Rf;               // Wp rows
    float*  pb   = (float*)(sP + Rf);      // partials [8 cols][8 waves][64]

    const int tid = threadIdx.x;
    const int b  = tid & 63;
    const int wv = tid >> 6;
    const int c0 = blockIdx.x * 2;

    // ---- stage this block's 2 columns of every matrix into LDS
    for (int k = tid; k < LIN; k += NTHR) {
        sRES[k] = *(const float2*)&Win[(size_t)k * Hf + c0];
        sGx[k]  = *(const float2*)&Wg[(size_t)k * Hf + c0];
    }
    for (int k = tid; k < LIN + Hf; k += NTHR) {
        sZ[k] = *(const float2*)&Wz[(size_t)k * Hf + c0];
        sR[k] = *(const float2*)&Wr[(size_t)k * Hf + c0];
        sC[k] = *(const float2*)&Wc[(size_t)k * Hf + c0];
    }
    for (int k = tid; k < Hf; k += NTHR) {
        sRES[LIN + k] = *(const float2*)&Wres[(size_t)k * Hf + c0];
        sGh[k] = *(const float2*)&Wg[(size_t)(LIN + k) * Hf + c0];
        sGr[k] = *(const float2*)&Wg[(size_t)(LIN + Hf + k) * Hf + c0];
        sP[k]  = *(const float2*)&Wp[(size_t)k * Hf + c0];
    }
    __syncthreads();

    float* rc = rA; float* rn = rB; float* hc = hA; float* hn = hB;
    unsigned gen = 0;
    constexpr int CX = LIN / 8;

    for (int t = 0; t < Tt; ++t) {
        const float* xt = xT + (size_t)t * LIN * 64;

        // ================= phase A: r_new, z, rh, gx =================
        {
            float2 aRES = {0, 0}, aZ = {0, 0}, aRr = {0, 0}, aG = {0, 0};
            {
                const float* xb = xt + b;
                int kb = wv * CX;
#pragma unroll 8
                for (int k = kb; k < kb + CX; ++k) {
                    float xv = xb[k * 64];
                    float2 w;
                    w = sRES[k]; aRES.x = fmaf(w.x, xv, aRES.x); aRES.y = fmaf(w.y, xv, aRES.y);
                    w = sZ[k];   aZ.x   = fmaf(w.x, xv, aZ.x);   aZ.y   = fmaf(w.y, xv, aZ.y);
                    w = sR[k];   aRr.x  = fmaf(w.x, xv, aRr.x);  aRr.y  = fmaf(w.y, xv, aRr.y);
                    w = sGx[k];  aG.x   = fmaf(w.x, xv, aG.x);   aG.y   = fmaf(w.y, xv, aG.y);
                }
            }
            {
                const float* hb = hc + b;
                const float* rb = rc + b;
                int kb = wv * 64;
#pragma unroll 8
                for (int k = kb; k < kb + 64; ++k) {
                    float hv = hb[k * 64];
                    float rv = rb[k * 64];
                    float2 w;
                    w = sRES[LIN + k]; aRES.x = fmaf(w.x, rv, aRES.x); aRES.y = fmaf(w.y, rv, aRES.y);
                    w = sZ[LIN + k];   aZ.x   = fmaf(w.x, hv, aZ.x);   aZ.y   = fmaf(w.y, hv, aZ.y);
                    w = sR[LIN + k];   aRr.x  = fmaf(w.x, hv, aRr.x);  aRr.y  = fmaf(w.y, hv, aRr.y);
                }
            }
            pb[(0 * 8 + wv) * 64 + b] = aRES.x; pb[(1 * 8 + wv) * 64 + b] = aRES.y;
            pb[(2 * 8 + wv) * 64 + b] = aZ.x;   pb[(3 * 8 + wv) * 64 + b] = aZ.y;
            pb[(4 * 8 + wv) * 64 + b] = aRr.x;  pb[(5 * 8 + wv) * 64 + b] = aRr.y;
            pb[(6 * 8 + wv) * 64 + b] = aG.x;   pb[(7 * 8 + wv) * 64 + b] = aG.y;
            __syncthreads();
            {
                int col = wv;      // 8 cols: RES0,RES1,Z0,Z1,R0,R1,G0,G1
                float s = 0.f;
#pragma unroll
                for (int w2 = 0; w2 < 8; ++w2) s += pb[(col * 8 + w2) * 64 + b];
                int c = c0 + (col & 1);
                int ty = col >> 1;
                if (ty == 0) {
                    float ro = rc[c * 64 + b];
                    rn[c * 64 + b] = 0.7f * ro + 0.3f * tanhf(s);
                } else if (ty == 1) {
                    zT[c * 64 + b] = sigmoidf_(s + bz[c]);
                } else if (ty == 2) {
                    rhT[c * 64 + b] = sigmoidf_(s + br[c]) * hc[c * 64 + b];
                } else {
                    gxT[c * 64 + b] = s;
                }
            }
            gsync(flags, ++gen);
        }

        // ================= phase B: cand->h_gru, p, gg =================
        {
            float2 aC = {0, 0}, aP = {0, 0}, aGr = {0, 0};
            {
                const float* xb = xt + b;
                int kb = wv * CX;
#pragma unroll 8
                for (int k = kb; k < kb + CX; ++k) {
                    float xv = xb[k * 64];
                    float2 w = sC[k];
                    aC.x = fmaf(w.x, xv, aC.x); aC.y = fmaf(w.y, xv, aC.y);
                }
            }
            {
                const float* rhb = rhT + b;
                const float* rnb = rn + b;
                int kb = wv * 64;
#pragma unroll 8
                for (int k = kb; k < kb + 64; ++k) {
                    float rhv = rhb[k * 64];
                    float rnv = rnb[k * 64];
                    float2 w;
                    w = sC[LIN + k]; aC.x  = fmaf(w.x, rhv, aC.x);  aC.y  = fmaf(w.y, rhv, aC.y);
                    w = sP[k];       aP.x  = fmaf(w.x, rnv, aP.x);  aP.y  = fmaf(w.y, rnv, aP.y);
                    w = sGr[k];      aGr.x = fmaf(w.x, rnv, aGr.x); aGr.y = fmaf(w.y, rnv, aGr.y);
                }
            }
            pb[(0 * 8 + wv) * 64 + b] = aC.x;  pb[(1 * 8 + wv) * 64 + b] = aC.y;
            pb[(2 * 8 + wv) * 64 + b] = aP.x;  pb[(3 * 8 + wv) * 64 + b] = aP.y;
            pb[(4 * 8 + wv) * 64 + b] = aGr.x; pb[(5 * 8 + wv) * 64 + b] = aGr.y;
            __syncthreads();
            if (wv < 6) {
                int col = wv;      // C0,C1,P0,P1,GR0,GR1
                float s = 0.f;
#pragma unroll
                for (int w2 = 0; w2 < 8; ++w2) s += pb[(col * 8 + w2) * 64 + b];
                int c = c0 + (col & 1);
                int ty = col >> 1;
                if (ty == 0) {
                    float cand = tanhf(s + bc[c]);
                    float z = zT[c * 64 + b], h = hc[c * 64 + b];
                    hgT[c * 64 + b] = (1.f - z) * h + z * cand;
                } else if (ty == 1) {
                    pT[c * 64 + b] = tanhf(s + bp[c]);
                } else {
                    ggT[c * 64 + b] = s + gxT[c * 64 + b];
                }
            }
            gsync(flags, ++gen);
        }

        // ================= phase C: g, h_new =================
        {
            float2 aGh = {0, 0};
            {
                const float* hgb = hgT + b;
                int kb = wv * 64;
#pragma unroll 8
                for (int k = kb; k < kb + 64; ++k) {
                    float hgv = hgb[k * 64];
                    float2 w = sGh[k];
                    aGh.x = fmaf(w.x, hgv, aGh.x); aGh.y = fmaf(w.y, hgv, aGh.y);
                }
            }
            pb[(0 * 8 + wv) * 64 + b] = aGh.x;
            pb[(1 * 8 + wv) * 64 + b] = aGh.y;
            __syncthreads();
            if (wv < 2) {
                int col = wv;
                float s = 0.f;
#pragma unroll
                for (int w2 = 0; w2 < 8; ++w2) s += pb[(col * 8 + w2) * 64 + b];
                int c = c0 + col;
                float g = sigmoidf_(s + ggT[c * 64 + b] + bg[c]);
                float hg = hgT[c * 64 + b];
                float hnv = (1.f - g) * hg + g * pT[c * 64 + b];
                hn[c * 64 + b] = hnv;
                if (WRITE_Y) y[(size_t)t * (Hf * 64) + c * 64 + b] = hnv;
            }
            gsync(flags, ++gen);
        }

        float* tp = rc; rc = rn; rn = tp;
        tp = hc; hc = hn; hn = tp;
    }
}

// Head: hid = relu(last@Wo1 + bo1)
__global__ __launch_bounds__(256) void head1_k(const float* __restrict__ hlast,
                                               const float* __restrict__ Wo1,
                                               const float* __restrict__ bo1,
                                               float* __restrict__ hidT) {
    int tid = threadIdx.x;
    int b = tid & 63, jg = tid >> 6;
    int j0 = blockIdx.x * 16 + jg * 4;
    float acc[4] = {0.f, 0.f, 0.f, 0.f};
    const float* ap = hlast + b;
    const float* wp = Wo1 + j0;
#pragma unroll 4
    for (int k = 0; k < Hf; ++k) {
        float xv = ap[k * 64];
        const float4 w = *reinterpret_cast<const float4*>(wp + k * 512);
        acc[0] = fmaf(w.x, xv, acc[0]);
        acc[1] = fmaf(w.y, xv, acc[1]);
        acc[2] = fmaf(w.z, xv, acc[2]);
        acc[3] = fmaf(w.w, xv, acc[3]);
    }
#pragma unroll
    for (int jj = 0; jj < 4; ++jj) {
        int j = j0 + jj;
        hidT[j * 64 + b] = fmaxf(acc[jj] + bo1[j], 0.f);
    }
}

__global__ __launch_bounds__(640) void head2_k(const float* __restrict__ hidT,
                                               const float* __restrict__ Wo2,
                                               const float* __restrict__ bo2,
                                               float* __restrict__ out) {
    int tid = threadIdx.x;
    if (tid >= Bsz * OUTF) return;
    int b = tid / OUTF, o = tid % OUTF;
    float acc = 0.f;
    for (int k = 0; k < Hf; ++k)
        acc = fmaf(hidT[k * 64 + b], Wo2[k * OUTF + o], acc);
    out[tid] = acc + bo2[o];
}

struct LayerW {
    const float *Win, *Wres, *Wz, *bz, *Wr, *br, *Wc, *bc, *Wg, *bg, *Wp, *bp;
};

extern "C" void kernel_launch(void* const* d_in, const int* in_sizes, int n_in,
                              void* d_out, int out_size, void* d_ws, size_t ws_size,
                              hipStream_t stream) {
    const float* x = (const float*)d_in[0];
    LayerW L[2];
    int idx = 1;
    for (int li = 0; li < 2; ++li) {
        L[li].Win  = (const float*)d_in[idx++];
        L[li].Wres = (const float*)d_in[idx++];
        L[li].Wz   = (const float*)d_in[idx++];
        L[li].bz   = (const float*)d_in[idx++];
        L[li].Wr   = (const float*)d_in[idx++];
        L[li].br   = (const float*)d_in[idx++];
        L[li].Wc   = (const float*)d_in[idx++];
        L[li].bc   = (const float*)d_in[idx++];
        L[li].Wg   = (const float*)d_in[idx++];
        L[li].bg   = (const float*)d_in[idx++];
        L[li].Wp   = (const float*)d_in[idx++];
        L[li].bp   = (const float*)d_in[idx++];
    }
    const float* Wo1 = (const float*)d_in[idx++];
    const float* bo1 = (const float*)d_in[idx++];
    const float* Wo2 = (const float*)d_in[idx++];
    const float* bo2 = (const float*)d_in[idx++];

    char* ws = (char*)d_ws;
    size_t off = 0;
    auto walloc = [&](size_t bytes) -> float* {
        float* p = (float*)(ws + off);
        off += (bytes + 255) & ~(size_t)255;
        return p;
    };
    const size_t STATE = (size_t)Hf * 64 * sizeof(float); // 128 KiB
    float* xT0 = walloc((size_t)Tt * INF * 64 * sizeof(float)); // 33.5 MB
    float* y0  = walloc((size_t)Tt * Hf * 64 * sizeof(float));  // 67 MB
    float* rA  = walloc(STATE);
    float* rB  = walloc(STATE);
    float* hA  = walloc(STATE);
    float* hB  = walloc(STATE);
    float* zT  = walloc(STATE);
    float* rhT = walloc(STATE);
    float* gxT = walloc(STATE);
    float* hgT = walloc(STATE);
    float* pT  = walloc(STATE);
    float* ggT = walloc(STATE);
    float* hidT = walloc(STATE);
    unsigned* flags = (unsigned*)walloc(NBLK * sizeof(unsigned));
    (void)ws_size;

    // Allow 64KB dynamic LDS (no-op if already allowed); host-side, capture-safe.
    hipFuncSetAttribute((const void*)esn_persist_k<INF, true>,
                        hipFuncAttributeMaxDynamicSharedMemorySize, SMEM_BYTES);
    hipFuncSetAttribute((const void*)esn_persist_k<Hf, false>,
                        hipFuncAttributeMaxDynamicSharedMemorySize, SMEM_BYTES);

    transpose_x_k<<<dim3(Tt, INF / 64), 256, 0, stream>>>(x, xT0);

    // ---- layer 0
    hipMemsetAsync(flags, 0, NBLK * sizeof(unsigned), stream);
    hipMemsetAsync(rA, 0, STATE, stream);
    hipMemsetAsync(hA, 0, STATE, stream);
    esn_persist_k<INF, true><<<NBLK, NTHR, SMEM_BYTES, stream>>>(
        xT0, y0, rA, rB, hA, hB, zT, rhT, gxT, hgT, pT, ggT,
        L[0].Win, L[0].Wres, L[0].Wz, L[0].bz, L[0].Wr, L[0].br,
        L[0].Wc, L[0].bc, L[0].Wg, L[0].bg, L[0].Wp, L[0].bp, flags);

    // ---- layer 1
    hipMemsetAsync(flags, 0, NBLK * sizeof(unsigned), stream);
    hipMemsetAsync(rA, 0, STATE, stream);
    hipMemsetAsync(hA, 0, STATE, stream);
    esn_persist_k<Hf, false><<<NBLK, NTHR, SMEM_BYTES, stream>>>(
        y0, nullptr, rA, rB, hA, hB, zT, rhT, gxT, hgT, pT, ggT,
        L[1].Win, L[1].Wres, L[1].Wz, L[1].bz, L[1].Wr, L[1].br,
        L[1].Wc, L[1].bc, L[1].Wg, L[1].bg, L[1].Wp, L[1].bp, flags);

    // Tt=512 steps: t=511 (odd) wrote the A-buffer -> final h is in hA.
    head1_k<<<dim3(32, 1), 256, 0, stream>>>(hA, Wo1, bo1, hidT);
    head2_k<<<dim3(1, 1), 640, 0, stream>>>(hidT, Wo2, bo2, (float*)d_out);
}

// Round 3
// 31068.384 us; speedup vs baseline: 5.0076x; 2.6887x over previous
//
#include <hip/hip_runtime.h>
#include <math.h>

static constexpr int Bsz = 64;
static constexpr int Tt  = 512;
static constexpr int INF = 256;
static constexpr int Hf  = 512;
static constexpr int OUTF = 10;
static constexpr int NBLK = 256;   // 128 col-groups x 2 batch-halves
static constexpr int NTHR = 1024;  // 16 waves

__device__ __forceinline__ float sigmoidf_(float x) {
    return 1.0f / (1.0f + __expf(-x));
}

// Agent-scope coherent (LLC) scalar access: bypasses L1/L2, no fences.
__device__ __forceinline__ float ldc(const float* p) {
    return __hip_atomic_load(const_cast<float*>(p), __ATOMIC_RELAXED, __HIP_MEMORY_SCOPE_AGENT);
}
__device__ __forceinline__ void stc(float* p, float v) {
    __hip_atomic_store(p, v, __ATOMIC_RELAXED, __HIP_MEMORY_SCOPE_AGENT);
}

// Per-half flag barrier. Caller guarantees all data stores were issued before;
// the first __syncthreads drains each wave's vmcnt (sc1 stores are then at LLC).
__device__ __forceinline__ void gsync(unsigned* flags, int myflag, int pollbase, unsigned gen) {
    __syncthreads();
    const int tid = threadIdx.x;
    if (tid == 0)
        __hip_atomic_store(&flags[myflag], gen, __ATOMIC_RELAXED, __HIP_MEMORY_SCOPE_AGENT);
    if (tid < 128) {
        const unsigned* f = &flags[pollbase + tid];
        while (__hip_atomic_load(const_cast<unsigned*>(f), __ATOMIC_RELAXED, __HIP_MEMORY_SCOPE_AGENT) < gen)
            __builtin_amdgcn_s_sleep(2);
    }
    __syncthreads();
}

// x (B,T,IN) -> xT (T,IN,B)
__global__ __launch_bounds__(256) void transpose_x_k(const float* __restrict__ x,
                                                     float* __restrict__ xT) {
    __shared__ float tile[64][65];
    int t  = blockIdx.x;
    int k0 = blockIdx.y * 64;
    int tid = threadIdx.x;
#pragma unroll
    for (int i = 0; i < 16; ++i) {
        int idx = i * 256 + tid;
        int bb = idx >> 6, kk = idx & 63;
        tile[bb][kk] = x[(size_t)bb * Tt * INF + (size_t)t * INF + k0 + kk];
    }
    __syncthreads();
#pragma unroll
    for (int i = 0; i < 16; ++i) {
        int idx = i * 256 + tid;
        int kk = idx >> 6, bb = idx & 63;
        xT[(size_t)t * INF * 64 + (size_t)(k0 + kk) * 64 + bb] = tile[bb][kk];
    }
}

#define FMA2(a, w, v) { a.x = fmaf((w).x, (v), a.x); a.y = fmaf((w).y, (v), a.y); }

// Persistent layer kernel. Block (cg, bh): cols [cg*4, cg*4+4), batches [bh*32, bh*32+32).
// Weights for its 4 cols LDS-resident as float4 rows; lane = b(0..31) + 32*cs,
// lane covers cols {c0+2cs, c0+2cs+1} via float2 LDS reads (2-way broadcast, free).
template<int LIN, bool WRITE_Y>
__global__ __launch_bounds__(NTHR, 4) void esn_persist_k(
    const float* __restrict__ xT, float* __restrict__ y,
    float* rA, float* rB, float* hA, float* hB,
    float* rhB, float* hgB,
    const float* __restrict__ Win, const float* __restrict__ Wres,
    const float* __restrict__ Wz, const float* __restrict__ bz,
    const float* __restrict__ Wr, const float* __restrict__ br,
    const float* __restrict__ Wc, const float* __restrict__ bc,
    const float* __restrict__ Wg, const float* __restrict__ bg,
    const float* __restrict__ Wp, const float* __restrict__ bp,
    unsigned* flags)
{
    constexpr int R4 = LIN + 512;              // rows of RES/Z/R/C mats
    constexpr int ROWS = 4 * R4 + LIN + 3 * 512;
    constexpr int CX = LIN / 16;               // x-rows per wave

    extern __shared__ char smem[];
    float4* sW  = (float4*)smem;               // ROWS float4 rows
    float*  pb  = (float*)(smem + (size_t)ROWS * 16);  // partials: 4*16*64*2 floats
    float*  lz  = pb + 8192;                   // [4][32] locals
    float*  lgx = lz + 128;
    float*  lp  = lgx + 128;
    float*  lgg = lp + 128;
    float*  lhg = lgg + 128;

    const int tid  = threadIdx.x;
    const int lane = tid & 63;
    const int wv   = tid >> 6;                 // 0..15
    const int b    = lane & 31;
    const int cs   = lane >> 5;                // 0/1
    const int cg   = blockIdx.x & 127;
    const int bh   = blockIdx.x >> 7;
    const int c0   = cg * 4;
    const int boff = bh * 32;
    const int myflag = bh * 128 + cg;
    const int pollbase = bh * 128;

    float4* wRES = sW;
    float4* wZ   = wRES + R4;
    float4* wR   = wZ + R4;
    float4* wC   = wR + R4;
    float4* wGx  = wC + R4;
    float4* wGh  = wGx + LIN;
    float4* wGr  = wGh + 512;
    float4* wP   = wGr + 512;

    // ---- stage 4 columns of every matrix into LDS
    for (int k = tid; k < LIN; k += NTHR) {
        wRES[k] = *(const float4*)&Win[(size_t)k * 512 + c0];
        wGx[k]  = *(const float4*)&Wg[(size_t)k * 512 + c0];
    }
    for (int k = tid; k < R4; k += NTHR) {
        wZ[k] = *(const float4*)&Wz[(size_t)k * 512 + c0];
        wR[k] = *(const float4*)&Wr[(size_t)k * 512 + c0];
        wC[k] = *(const float4*)&Wc[(size_t)k * 512 + c0];
    }
    for (int k = tid; k < 512; k += NTHR) {
        wRES[LIN + k] = *(const float4*)&Wres[(size_t)k * 512 + c0];
        wGh[k] = *(const float4*)&Wg[(size_t)(LIN + k) * 512 + c0];
        wGr[k] = *(const float4*)&Wg[(size_t)(LIN + 512 + k) * 512 + c0];
        wP[k]  = *(const float4*)&Wp[(size_t)k * 512 + c0];
    }
    __syncthreads();

#define W2(base, idx) (((const float2*)(base))[(size_t)(idx) * 2 + cs])

    float* rc = rA; float* rn = rB; float* hc = hA; float* hn = hB;
    unsigned gen = 0;

    for (int t = 0; t < Tt; ++t) {
        const float* xt = xT + (size_t)t * LIN * 64;

        // ============ phase A: r_new, z, rh, gx ============
        {
            float2 aRES = {0, 0}, aZ = {0, 0}, aR = {0, 0}, aG = {0, 0};
            {
                const float* xb = xt + boff + b;
                int k0 = wv * CX;
#pragma unroll 8
                for (int k = k0; k < k0 + CX; ++k) {
                    float xv = xb[k * 64];
                    float2 w;
                    w = W2(wRES, k); FMA2(aRES, w, xv);
                    w = W2(wZ, k);   FMA2(aZ, w, xv);
                    w = W2(wR, k);   FMA2(aR, w, xv);
                    w = W2(wGx, k);  FMA2(aG, w, xv);
                }
            }
            {
                int k0 = wv * 32;
#pragma unroll 8
                for (int k = k0; k < k0 + 32; ++k) {
                    float rv = ldc(rc + k * 64 + boff + b);
                    float hv = ldc(hc + k * 64 + boff + b);
                    float2 w;
                    w = W2(wRES, LIN + k); FMA2(aRES, w, rv);
                    w = W2(wZ, LIN + k);   FMA2(aZ, w, hv);
                    w = W2(wR, LIN + k);   FMA2(aR, w, hv);
                }
            }
            float2* pb2 = (float2*)pb;
            pb2[(0 * 16 + wv) * 64 + lane] = aRES;
            pb2[(1 * 16 + wv) * 64 + lane] = aZ;
            pb2[(2 * 16 + wv) * 64 + lane] = aR;
            pb2[(3 * 16 + wv) * 64 + lane] = aG;
            __syncthreads();
            if (tid < 512) {
                int m = tid >> 7, rem = tid & 127, c = rem >> 5, bb = rem & 31;
                int pl = (bb + 32 * (c >> 1)) * 2 + (c & 1);
                float s = 0.f;
#pragma unroll
                for (int w = 0; w < 16; ++w) s += pb[(m * 16 + w) * 128 + pl];
                int cab = c0 + c;
                int gi = cab * 64 + boff + bb;
                if (m == 0) {
                    float ro = ldc(rc + gi);
                    stc(rn + gi, 0.7f * ro + 0.3f * tanhf(s));
                } else if (m == 1) {
                    lz[c * 32 + bb] = sigmoidf_(s + bz[cab]);
                } else if (m == 2) {
                    float hv = ldc(hc + gi);
                    stc(rhB + gi, sigmoidf_(s + br[cab]) * hv);
                } else {
                    lgx[c * 32 + bb] = s;
                }
            }
            gsync(flags, myflag, pollbase, ++gen);
        }

        // ============ phase B: h_gru, p, gg ============
        {
            float2 aC = {0, 0}, aP = {0, 0}, aGr = {0, 0};
            {
                const float* xb = xt + boff + b;
                int k0 = wv * CX;
#pragma unroll 8
                for (int k = k0; k < k0 + CX; ++k) {
                    float xv = xb[k * 64];
                    float2 w = W2(wC, k);
                    FMA2(aC, w, xv);
                }
            }
            {
                int k0 = wv * 32;
#pragma unroll 8
                for (int k = k0; k < k0 + 32; ++k) {
                    float rnv = ldc(rn + k * 64 + boff + b);
                    float rhv = ldc(rhB + k * 64 + boff + b);
                    float2 w;
                    w = W2(wC, LIN + k); FMA2(aC, w, rhv);
                    w = W2(wP, k);       FMA2(aP, w, rnv);
                    w = W2(wGr, k);      FMA2(aGr, w, rnv);
                }
            }
            float2* pb2 = (float2*)pb;
            pb2[(0 * 16 + wv) * 64 + lane] = aC;
            pb2[(1 * 16 + wv) * 64 + lane] = aP;
            pb2[(2 * 16 + wv) * 64 + lane] = aGr;
            __syncthreads();
            if (tid < 384) {
                int m = tid >> 7, rem = tid & 127, c = rem >> 5, bb = rem & 31;
                int pl = (bb + 32 * (c >> 1)) * 2 + (c & 1);
                float s = 0.f;
#pragma unroll
                for (int w = 0; w < 16; ++w) s += pb[(m * 16 + w) * 128 + pl];
                int cab = c0 + c;
                int gi = cab * 64 + boff + bb;
                if (m == 0) {
                    float cand = tanhf(s + bc[cab]);
                    float z = lz[c * 32 + bb];
                    float hv = ldc(hc + gi);
                    float hg = (1.f - z) * hv + z * cand;
                    stc(hgB + gi, hg);
                    lhg[c * 32 + bb] = hg;
                } else if (m == 1) {
                    lp[c * 32 + bb] = tanhf(s + bp[cab]);
                } else {
                    lgg[c * 32 + bb] = s + lgx[c * 32 + bb];
                }
            }
            gsync(flags, myflag, pollbase, ++gen);
        }

        // ============ phase C: g, h_new ============
        {
            float2 aGh = {0, 0};
            {
                int k0 = wv * 32;
#pragma unroll 8
                for (int k = k0; k < k0 + 32; ++k) {
                    float hgv = ldc(hgB + k * 64 + boff + b);
                    float2 w = W2(wGh, k);
                    FMA2(aGh, w, hgv);
                }
            }
            ((float2*)pb)[(0 * 16 + wv) * 64 + lane] = aGh;
            __syncthreads();
            if (tid < 128) {
                int c = tid >> 5, bb = tid & 31;
                int pl = (bb + 32 * (c >> 1)) * 2 + (c & 1);
                float s = 0.f;
#pragma unroll
                for (int w = 0; w < 16; ++w) s += pb[w * 128 + pl];
                int cab = c0 + c;
                int gi = cab * 64 + boff + bb;
                float g = sigmoidf_(s + lgg[c * 32 + bb] + bg[cab]);
                float hgv = lhg[c * 32 + bb];
                float hnv = (1.f - g) * hgv + g * lp[c * 32 + bb];
                stc(hn + gi, hnv);
                if (WRITE_Y) y[(size_t)t * (Hf * 64) + gi] = hnv;   // normal store, next kernel reads
            }
            gsync(flags, myflag, pollbase, ++gen);
        }

        float* tp = rc; rc = rn; rn = tp;
        tp = hc; hc = hn; hn = tp;
    }
#undef W2
}

// Head: hid = relu(last@Wo1 + bo1)
__global__ __launch_bounds__(256) void head1_k(const float* __restrict__ hlast,
                                               const float* __restrict__ Wo1,
                                               const float* __restrict__ bo1,
                                               float* __restrict__ hidT) {
    int tid = threadIdx.x;
    int b = tid & 63, jg = tid >> 6;
    int j0 = blockIdx.x * 16 + jg * 4;
    float acc[4] = {0.f, 0.f, 0.f, 0.f};
    const float* ap = hlast + b;
    const float* wp = Wo1 + j0;
#pragma unroll 4
    for (int k = 0; k < Hf; ++k) {
        float xv = ap[k * 64];
        const float4 w = *reinterpret_cast<const float4*>(wp + k * 512);
        acc[0] = fmaf(w.x, xv, acc[0]);
        acc[1] = fmaf(w.y, xv, acc[1]);
        acc[2] = fmaf(w.z, xv, acc[2]);
        acc[3] = fmaf(w.w, xv, acc[3]);
    }
#pragma unroll
    for (int jj = 0; jj < 4; ++jj) {
        int j = j0 + jj;
        hidT[j * 64 + b] = fmaxf(acc[jj] + bo1[j], 0.f);
    }
}

__global__ __launch_bounds__(640) void head2_k(const float* __restrict__ hidT,
                                               const float* __restrict__ Wo2,
                                               const float* __restrict__ bo2,
                                               float* __restrict__ out) {
    int tid = threadIdx.x;
    if (tid >= Bsz * OUTF) return;
    int b = tid / OUTF, o = tid % OUTF;
    float acc = 0.f;
    for (int k = 0; k < Hf; ++k)
        acc = fmaf(hidT[k * 64 + b], Wo2[k * OUTF + o], acc);
    out[tid] = acc + bo2[o];
}

struct LayerW {
    const float *Win, *Wres, *Wz, *bz, *Wr, *br, *Wc, *bc, *Wg, *bg, *Wp, *bp;
};

extern "C" void kernel_launch(void* const* d_in, const int* in_sizes, int n_in,
                              void* d_out, int out_size, void* d_ws, size_t ws_size,
                              hipStream_t stream) {
    const float* x = (const float*)d_in[0];
    LayerW L[2];
    int idx = 1;
    for (int li = 0; li < 2; ++li) {
        L[li].Win  = (const float*)d_in[idx++];
        L[li].Wres = (const float*)d_in[idx++];
        L[li].Wz   = (const float*)d_in[idx++];
        L[li].bz   = (const float*)d_in[idx++];
        L[li].Wr   = (const float*)d_in[idx++];
        L[li].br   = (const float*)d_in[idx++];
        L[li].Wc   = (const float*)d_in[idx++];
        L[li].bc   = (const float*)d_in[idx++];
        L[li].Wg   = (const float*)d_in[idx++];
        L[li].bg   = (const float*)d_in[idx++];
        L[li].Wp   = (const float*)d_in[idx++];
        L[li].bp   = (const float*)d_in[idx++];
    }
    const float* Wo1 = (const float*)d_in[idx++];
    const float* bo1 = (const float*)d_in[idx++];
    const float* Wo2 = (const float*)d_in[idx++];
    const float* bo2 = (const float*)d_in[idx++];

    char* ws = (char*)d_ws;
    size_t off = 0;
    auto walloc = [&](size_t bytes) -> float* {
        float* p = (float*)(ws + off);
        off += (bytes + 255) & ~(size_t)255;
        return p;
    };
    const size_t STATE = (size_t)Hf * 64 * sizeof(float); // 128 KiB
    float* xT0 = walloc((size_t)Tt * INF * 64 * sizeof(float)); // 33.5 MB
    float* y0  = walloc((size_t)Tt * Hf * 64 * sizeof(float));  // 67 MB
    float* rA  = walloc(STATE);
    float* rB  = walloc(STATE);
    float* hA  = walloc(STATE);
    float* hB  = walloc(STATE);
    float* rhB = walloc(STATE);
    float* hgB = walloc(STATE);
    float* hidT = walloc(STATE);
    unsigned* flags = (unsigned*)walloc(NBLK * sizeof(unsigned));
    (void)ws_size;

    constexpr unsigned SMEM0 = (4 * (INF + 512) + INF + 3 * 512) * 16 + 32768 + 5 * 128 * 4; // 113152
    constexpr unsigned SMEM1 = (4 * (Hf + 512) + Hf + 3 * 512) * 16 + 32768 + 5 * 128 * 4;   // 133632
    hipFuncSetAttribute((const void*)esn_persist_k<INF, true>,
                        hipFuncAttributeMaxDynamicSharedMemorySize, SMEM0);
    hipFuncSetAttribute((const void*)esn_persist_k<Hf, false>,
                        hipFuncAttributeMaxDynamicSharedMemorySize, SMEM1);

    transpose_x_k<<<dim3(Tt, INF / 64), 256, 0, stream>>>(x, xT0);

    // ---- layer 0
    hipMemsetAsync(flags, 0, NBLK * sizeof(unsigned), stream);
    hipMemsetAsync(rA, 0, STATE, stream);
    hipMemsetAsync(hA, 0, STATE, stream);
    esn_persist_k<INF, true><<<NBLK, NTHR, SMEM0, stream>>>(
        xT0, y0, rA, rB, hA, hB, rhB, hgB,
        L[0].Win, L[0].Wres, L[0].Wz, L[0].bz, L[0].Wr, L[0].br,
        L[0].Wc, L[0].bc, L[0].Wg, L[0].bg, L[0].Wp, L[0].bp, flags);

    // ---- layer 1
    hipMemsetAsync(flags, 0, NBLK * sizeof(unsigned), stream);
    hipMemsetAsync(rA, 0, STATE, stream);
    hipMemsetAsync(hA, 0, STATE, stream);
    esn_persist_k<Hf, false><<<NBLK, NTHR, SMEM1, stream>>>(
        y0, nullptr, rA, rB, hA, hB, rhB, hgB,
        L[1].Win, L[1].Wres, L[1].Wz, L[1].bz, L[1].Wr, L[1].br,
        L[1].Wc, L[1].bc, L[1].Wg, L[1].bg, L[1].Wp, L[1].bp, flags);

    // 512 steps (even) -> final h is back in hA.
    head1_k<<<dim3(32, 1), 256, 0, stream>>>(hA, Wo1, bo1, hidT);
    head2_k<<<dim3(1, 1), 640, 0, stream>>>(hidT, Wo2, bo2, (float*)d_out);
}